// Round 6
// baseline (24.916 us; speedup 1.0000x reference)
//
#include <hip/hip_runtime.h>

#define HH 128
#define WW 192
#define HW (HH * WW)

typedef float f32x4 __attribute__((ext_vector_type(4)));

__device__ __forceinline__ float relu(float v) { return fmaxf(v, 0.0f); }

// LDS weight layout (176 floats; every f32x4 row 16B-aligned):
// [0..7] w0x[o]  [8..15] w0y[o]  [16..23] b0[o]
// [24..87] w0t[ch][o] (8 rows of 8)  [88..151] w1t[i][o] (8 rows of 8)
// [152..159] w2[o]  [160..167] b1[o]  [168] b2

__global__ __launch_bounds__(256, 3) void dmh_kernel(
    const float* __restrict__ mask_feats,   // (4,8,128,192)
    const float* __restrict__ params,       // (128,169)
    const float* __restrict__ locs,         // (128,2)
    const float* __restrict__ soi,          // (5,)
    const int*   __restrict__ im_inds,      // (128,)
    const int*   __restrict__ fpn_levels,   // (128,)
    const int*   __restrict__ stride_p,     // scalar (=8)
    float*       __restrict__ out)          // (128,1,256,384)
{
    const int tid = threadIdx.x;
    const int c0 = blockIdx.x * 64;   // source col tile origin
    const int r0 = blockIdx.y * 32;   // source row tile origin
    const int n  = blockIdx.z;        // instance

    __shared__ float sW[176];
    __shared__ float tile[33 * 66];   // rows -1..31 -> 0..32, cols -1..63 -> 0..64

    // ---- stage + transpose weights into LDS ----
    if (tid < 169) {
        float v = params[(size_t)n * 169 + tid];
        int d;
        if (tid < 80)       { int o = tid / 10, r = tid - o * 10;
                              d = (r == 0) ? o : (r == 1) ? (8 + o) : (24 + (r - 2) * 8 + o); }
        else if (tid < 144) { int t = tid - 80, o = t >> 3, i = t & 7; d = 88 + i * 8 + o; }
        else if (tid < 152) d = 152 + (tid - 144);
        else if (tid < 160) d = 16 + (tid - 152);
        else if (tid < 168) d = 160 + (tid - 160);
        else                d = 168;
        sW[d] = v;
    }

    const int   stride = *stride_p;                 // 8
    const float half   = 0.5f * (float)stride;      // 4.0
    const float locx = locs[2 * n + 0];
    const float locy = locs[2 * n + 1];
    const float inv  = 1.0f / soi[fpn_levels[n]];
    const float* fb  = mask_feats + (size_t)im_inds[n] * 8 * HW;

    // ---- interior geometry: 2 rows x 4 cols per thread; issue all 16 loads
    //      BEFORE the staging barrier (latency hidden under barrier wait) ----
    const int ir  = (tid >> 4) * 2;     // 0,2,...,30
    const int ic  = (tid & 15) * 4;     // 0,4,...,60
    const int rA  = r0 + ir;            // always in-bounds
    const int cc0 = c0 + ic;
    const float* fpA = fb + rA * WW + cc0;

    f32x4 xA[8], xB[8];
    #pragma unroll
    for (int ch = 0; ch < 8; ++ch) {
        xA[ch] = *reinterpret_cast<const f32x4*>(fpA + ch * HW);
        xB[ch] = *reinterpret_cast<const f32x4*>(fpA + ch * HW + WW);
    }

    __syncthreads();

    const f32x4* __restrict__ sW4 = reinterpret_cast<const f32x4*>(sW);

    // ---------- phase 1a: interior MLP, 8 px per thread ----------
    {
        const float rxd = -(float)stride * inv;
        float rx[4];
        rx[0] = (locx - (float)(cc0 * stride) - half) * inv;
        rx[1] = rx[0] + rxd; rx[2] = rx[1] + rxd; rx[3] = rx[2] + rxd;
        const float ryA = (locy - (float)(rA * stride) - half) * inv;
        const float ryB = ryA - (float)stride * inv;

        f32x4 w0xL = sW4[0], w0xH = sW4[1];
        f32x4 w0yL = sW4[2], w0yH = sW4[3];
        f32x4 b0L  = sW4[4], b0H  = sW4[5];

        float hA[8][4], hB[8][4];
        #pragma unroll
        for (int o = 0; o < 8; ++o) {
            float wx = (o < 4) ? w0xL[o] : w0xH[o - 4];
            float wy = (o < 4) ? w0yL[o] : w0yH[o - 4];
            float b  = (o < 4) ? b0L[o]  : b0H[o - 4];
            float tA = fmaf(wy, ryA, b);
            float tB = fmaf(wy, ryB, b);
            #pragma unroll
            for (int j = 0; j < 4; ++j) {
                hA[o][j] = fmaf(wx, rx[j], tA);
                hB[o][j] = fmaf(wx, rx[j], tB);
            }
        }
        #pragma unroll
        for (int ch = 0; ch < 8; ++ch) {
            f32x4 wL = sW4[6 + 2 * ch];
            f32x4 wH = sW4[7 + 2 * ch];
            #pragma unroll
            for (int o = 0; o < 8; ++o) {
                float w = (o < 4) ? wL[o] : wH[o - 4];
                #pragma unroll
                for (int j = 0; j < 4; ++j) {
                    hA[o][j] = fmaf(w, xA[ch][j], hA[o][j]);
                    hB[o][j] = fmaf(w, xB[ch][j], hB[o][j]);
                }
            }
        }

        float aA[8][4], aB[8][4];
        {
            f32x4 b1L = sW4[40], b1H = sW4[41];
            #pragma unroll
            for (int o = 0; o < 8; ++o) {
                float b = (o < 4) ? b1L[o] : b1H[o - 4];
                #pragma unroll
                for (int j = 0; j < 4; ++j) { aA[o][j] = b; aB[o][j] = b; }
            }
        }
        #pragma unroll
        for (int i = 0; i < 8; ++i) {
            f32x4 wL = sW4[22 + 2 * i];
            f32x4 wH = sW4[23 + 2 * i];
            float vA[4], vB[4];
            #pragma unroll
            for (int j = 0; j < 4; ++j) { vA[j] = relu(hA[i][j]); vB[j] = relu(hB[i][j]); }
            #pragma unroll
            for (int o = 0; o < 8; ++o) {
                float w = (o < 4) ? wL[o] : wH[o - 4];
                #pragma unroll
                for (int j = 0; j < 4; ++j) {
                    aA[o][j] = fmaf(w, vA[j], aA[o][j]);
                    aB[o][j] = fmaf(w, vB[j], aB[o][j]);
                }
            }
        }

        f32x4 w2L = sW4[38], w2H = sW4[39];
        const float b2v = sW[168];
        float lgA[4] = {b2v, b2v, b2v, b2v};
        float lgB[4] = {b2v, b2v, b2v, b2v};
        #pragma unroll
        for (int o = 0; o < 8; ++o) {
            float w2 = (o < 4) ? w2L[o] : w2H[o - 4];
            #pragma unroll
            for (int j = 0; j < 4; ++j) {
                lgA[j] = fmaf(w2, relu(aA[o][j]), lgA[j]);
                lgB[j] = fmaf(w2, relu(aB[o][j]), lgB[j]);
            }
        }
        #pragma unroll
        for (int j = 0; j < 4; ++j) {
            tile[(ir + 1) * 66 + ic + 1 + j] = lgA[j];
            tile[(ir + 2) * 66 + ic + 1 + j] = lgB[j];
        }
    }

    // ---------- phase 1b: 97 halo px (row -1, col -1), scalar ----------
    if (tid < 97) {
        int r, c;
        if (tid < 65) { r = -1; c = tid - 1; }      // row -1, cols -1..63
        else          { r = tid - 65; c = -1; }     // rows 0..31, col -1
        int hr = min(max(r0 + r, 0), HH - 1);
        int hc = min(max(c0 + c, 0), WW - 1);
        const float* hfp = fb + hr * WW + hc;
        float rx  = (locx - (float)(hc * stride) - half) * inv;
        float ry2 = (locy - (float)(hr * stride) - half) * inv;
        float hh[8];
        #pragma unroll
        for (int o = 0; o < 8; ++o)
            hh[o] = fmaf(sW[o], rx, fmaf(sW[8 + o], ry2, sW[16 + o]));
        #pragma unroll
        for (int ch = 0; ch < 8; ++ch) {
            float x = hfp[ch * HW];
            #pragma unroll
            for (int o = 0; o < 8; ++o) hh[o] = fmaf(sW[24 + ch * 8 + o], x, hh[o]);
        }
        float aa[8];
        #pragma unroll
        for (int o = 0; o < 8; ++o) aa[o] = sW[160 + o];
        #pragma unroll
        for (int i = 0; i < 8; ++i) {
            float v = relu(hh[i]);
            #pragma unroll
            for (int o = 0; o < 8; ++o) aa[o] = fmaf(sW[88 + i * 8 + o], v, aa[o]);
        }
        float lg = sW[168];
        #pragma unroll
        for (int o = 0; o < 8; ++o) lg = fmaf(sW[152 + o], relu(aa[o]), lg);
        tile[(r + 1) * 66 + (c + 1)] = lg;
    }
    __syncthreads();

    // ---------- phase 2: x2 aligned upsample -> 64x128 output tile ----------
    const int kx = tid & 31;          // 32 groups of 4 output cols
    const int ky = tid >> 5;          // 8 row groups of 8 rows
    float* ob = out + ((size_t)n * 256 + 2 * r0) * 384 + 2 * c0 + 4 * kx;
    #pragma unroll
    for (int yy = 0; yy < 8; ++yy) {
        int yt = ky * 8 + yy;         // 0..63
        int iy = yt - 1;
        int rbl = iy >> 1;            // arithmetic shift handles iy=-1
        int fy = iy & 1;
        float wy0 = fy ? 0.5f : 1.0f;
        float wy1 = fy ? 0.5f : 0.0f;
        int sr  = rbl + 1;            // in [0,32]
        int sr2 = sr + fy;            // in [0,32]
        const float* ra = &tile[sr  * 66 + 2 * kx];
        const float* rc = &tile[sr2 * 66 + 2 * kx];
        float t0 = fmaf(wy1, rc[0], wy0 * ra[0]);
        float t1 = fmaf(wy1, rc[1], wy0 * ra[1]);
        float t2 = fmaf(wy1, rc[2], wy0 * ra[2]);
        float4 o4;
        o4.x = 0.5f * (t0 + t1);
        o4.y = t1;
        o4.z = 0.5f * (t1 + t2);
        o4.w = t2;
        *reinterpret_cast<float4*>(ob + (size_t)yt * 384) = o4;
    }
}

extern "C" void kernel_launch(void* const* d_in, const int* in_sizes, int n_in,
                              void* d_out, int out_size, void* d_ws, size_t ws_size,
                              hipStream_t stream) {
    const float* mask_feats = (const float*)d_in[0];
    const float* params     = (const float*)d_in[1];
    const float* locs       = (const float*)d_in[2];
    const float* soi        = (const float*)d_in[3];
    const int*   im_inds    = (const int*)d_in[4];
    const int*   fpn_levels = (const int*)d_in[5];
    const int*   stride_p   = (const int*)d_in[6];
    float* out = (float*)d_out;

    dim3 grid(WW / 64, HH / 32, 128);   // (3, 4, 128)
    dim3 block(256);
    dmh_kernel<<<grid, block, 0, stream>>>(
        mask_feats, params, locs, soi, im_inds, fpn_levels, stride_p, out);
}

// Round 7
// 24.116 us; speedup vs baseline: 1.0331x; 1.0331x over previous
//
#include <hip/hip_runtime.h>

#define HH 128
#define WW 192
#define HW (HH * WW)

typedef float f32x2 __attribute__((ext_vector_type(2)));

__device__ __forceinline__ float relu(float v) { return fmaxf(v, 0.0f); }

// LDS weight layout (176 floats):
// [0..7] w0x[o]  [8..15] w0y[o]  [16..23] b0[o]
// [24..87] w0t[ch][o] (8 rows of 8)  [88..151] w1t[i][o] (8 rows of 8)
// [152..159] w2[o]  [160..167] b1[o]  [168] b2

__global__ __launch_bounds__(256, 8) void dmh_kernel(
    const float* __restrict__ mask_feats,   // (4,8,128,192)
    const float* __restrict__ params,       // (128,169)
    const float* __restrict__ locs,         // (128,2)
    const float* __restrict__ soi,          // (5,)
    const int*   __restrict__ im_inds,      // (128,)
    const int*   __restrict__ fpn_levels,   // (128,)
    const int*   __restrict__ stride_p,     // scalar (=8)
    float*       __restrict__ out)          // (128,1,256,384)
{
    const int tid = threadIdx.x;
    const int c0 = blockIdx.x * 32;   // source col tile origin (32 wide)
    const int r0 = blockIdx.y * 16;   // source row tile origin (16 tall)
    const int n  = blockIdx.z;        // instance

    __shared__ float sW[176];
    __shared__ float tile[17 * 34];   // rows -1..15 -> 0..16, cols -1..31 -> 0..32

    // ---- issue weight load first ----
    float wv = 0.0f;
    if (tid < 169) wv = params[(size_t)n * 169 + tid];

    const int   stride = *stride_p;                 // 8
    const float half   = 0.5f * (float)stride;      // 4.0
    const float locx = locs[2 * n + 0];
    const float locy = locs[2 * n + 1];
    const float inv  = 1.0f / soi[fpn_levels[n]];
    const float* fb  = mask_feats + (size_t)im_inds[n] * 8 * HW;

    // ---- interior geometry: 1 row x 2 cols per thread; issue feat loads
    //      before the staging barrier ----
    const int row = tid >> 4;           // 0..15
    const int cp  = tid & 15;           // 0..15 -> cols 2cp, 2cp+1
    const int rr  = r0 + row;
    const int cc  = c0 + 2 * cp;
    const float* fp = fb + rr * WW + cc;

    f32x2 xv[8];
    #pragma unroll
    for (int ch = 0; ch < 8; ++ch)
        xv[ch] = *reinterpret_cast<const f32x2*>(fp + ch * HW);

    // ---- scatter weights (transposed) into LDS, then one barrier ----
    if (tid < 169) {
        int d;
        if (tid < 80)       { int o = tid / 10, r = tid - o * 10;
                              d = (r == 0) ? o : (r == 1) ? (8 + o) : (24 + (r - 2) * 8 + o); }
        else if (tid < 144) { int t = tid - 80, o = t >> 3, i = t & 7; d = 88 + i * 8 + o; }
        else if (tid < 152) d = 152 + (tid - 144);
        else if (tid < 160) d = 16 + (tid - 152);
        else if (tid < 168) d = 160 + (tid - 160);
        else                d = 168;
        sW[d] = wv;
    }
    __syncthreads();

    // ---------- phase 1a: interior MLP, 2 px per thread ----------
    {
        const float rxd = -(float)stride * inv;
        float rx0 = (locx - (float)(cc * stride) - half) * inv;
        float rx1 = rx0 + rxd;
        const float ry = (locy - (float)(rr * stride) - half) * inv;

        float h[8][2];
        #pragma unroll
        for (int o = 0; o < 8; ++o) {
            float t = fmaf(sW[8 + o], ry, sW[16 + o]);
            h[o][0] = fmaf(sW[o], rx0, t);
            h[o][1] = fmaf(sW[o], rx1, t);
        }
        #pragma unroll
        for (int ch = 0; ch < 8; ++ch) {
            float x0 = xv[ch][0], x1 = xv[ch][1];
            #pragma unroll
            for (int o = 0; o < 8; ++o) {
                float w = sW[24 + ch * 8 + o];
                h[o][0] = fmaf(w, x0, h[o][0]);
                h[o][1] = fmaf(w, x1, h[o][1]);
            }
        }
        float a[8][2];
        #pragma unroll
        for (int o = 0; o < 8; ++o) {
            float b = sW[160 + o];
            a[o][0] = b; a[o][1] = b;
        }
        #pragma unroll
        for (int i = 0; i < 8; ++i) {
            float v0 = relu(h[i][0]);
            float v1 = relu(h[i][1]);
            #pragma unroll
            for (int o = 0; o < 8; ++o) {
                float w = sW[88 + i * 8 + o];
                a[o][0] = fmaf(w, v0, a[o][0]);
                a[o][1] = fmaf(w, v1, a[o][1]);
            }
        }
        float lg0 = sW[168], lg1 = lg0;
        #pragma unroll
        for (int o = 0; o < 8; ++o) {
            float w2 = sW[152 + o];
            lg0 = fmaf(w2, relu(a[o][0]), lg0);
            lg1 = fmaf(w2, relu(a[o][1]), lg1);
        }
        tile[(row + 1) * 34 + 2 * cp + 1] = lg0;
        tile[(row + 1) * 34 + 2 * cp + 2] = lg1;
    }

    // ---------- phase 1b: 49 halo px (row -1, col -1), scalar ----------
    if (tid < 49) {
        int r, c;
        if (tid < 33) { r = -1; c = tid - 1; }      // row -1, cols -1..31
        else          { r = tid - 33; c = -1; }     // rows 0..15, col -1
        int hr = min(max(r0 + r, 0), HH - 1);
        int hc = min(max(c0 + c, 0), WW - 1);
        const float* hfp = fb + hr * WW + hc;
        float rx  = (locx - (float)(hc * stride) - half) * inv;
        float ry2 = (locy - (float)(hr * stride) - half) * inv;
        float hh[8];
        #pragma unroll
        for (int o = 0; o < 8; ++o)
            hh[o] = fmaf(sW[o], rx, fmaf(sW[8 + o], ry2, sW[16 + o]));
        #pragma unroll
        for (int ch = 0; ch < 8; ++ch) {
            float x = hfp[ch * HW];
            #pragma unroll
            for (int o = 0; o < 8; ++o) hh[o] = fmaf(sW[24 + ch * 8 + o], x, hh[o]);
        }
        float aa[8];
        #pragma unroll
        for (int o = 0; o < 8; ++o) aa[o] = sW[160 + o];
        #pragma unroll
        for (int i = 0; i < 8; ++i) {
            float v = relu(hh[i]);
            #pragma unroll
            for (int o = 0; o < 8; ++o) aa[o] = fmaf(sW[88 + i * 8 + o], v, aa[o]);
        }
        float lg = sW[168];
        #pragma unroll
        for (int o = 0; o < 8; ++o) lg = fmaf(sW[152 + o], relu(aa[o]), lg);
        tile[(r + 1) * 34 + (c + 1)] = lg;
    }
    __syncthreads();

    // ---------- phase 2: x2 aligned upsample -> 32x64 output tile ----------
    const int kx = tid & 15;          // 16 groups of 4 output cols (64 cols)
    const int ky = tid >> 4;          // 16 row groups of 2 rows (32 rows)
    float* ob = out + ((size_t)n * 256 + 2 * r0) * 384 + 2 * c0 + 4 * kx;
    #pragma unroll
    for (int yy = 0; yy < 2; ++yy) {
        int yt = ky * 2 + yy;         // 0..31
        int iy = 2 * r0 + yt - 1;
        int rbl = iy >> 1;            // arithmetic shift handles iy=-1
        int fy = iy & 1;
        float wy0 = fy ? 0.5f : 1.0f;
        float wy1 = fy ? 0.5f : 0.0f;
        int sr  = rbl - r0 + 1;       // in [0,16]
        int sr2 = sr + fy;            // in [0,16]
        const float* ra = &tile[sr  * 34 + 2 * kx];
        const float* rc = &tile[sr2 * 34 + 2 * kx];
        float t0 = fmaf(wy1, rc[0], wy0 * ra[0]);
        float t1 = fmaf(wy1, rc[1], wy0 * ra[1]);
        float t2 = fmaf(wy1, rc[2], wy0 * ra[2]);
        float4 o4;
        o4.x = 0.5f * (t0 + t1);
        o4.y = t1;
        o4.z = 0.5f * (t1 + t2);
        o4.w = t2;
        *reinterpret_cast<float4*>(ob + (size_t)yt * 384) = o4;
    }
}

extern "C" void kernel_launch(void* const* d_in, const int* in_sizes, int n_in,
                              void* d_out, int out_size, void* d_ws, size_t ws_size,
                              hipStream_t stream) {
    const float* mask_feats = (const float*)d_in[0];
    const float* params     = (const float*)d_in[1];
    const float* locs       = (const float*)d_in[2];
    const float* soi        = (const float*)d_in[3];
    const int*   im_inds    = (const int*)d_in[4];
    const int*   fpn_levels = (const int*)d_in[5];
    const int*   stride_p   = (const int*)d_in[6];
    float* out = (float*)d_out;

    dim3 grid(WW / 32, HH / 16, 128);   // (6, 8, 128)
    dim3 block(256);
    dmh_kernel<<<grid, block, 0, stream>>>(
        mask_feats, params, locs, soi, im_inds, fpn_levels, stride_p, out);
}

// Round 9
// 21.285 us; speedup vs baseline: 1.1706x; 1.1330x over previous
//
#include <hip/hip_runtime.h>

#define HH 128
#define WW 192
#define HW (HH * WW)

typedef float f32x4 __attribute__((ext_vector_type(4)));

__device__ __forceinline__ float relu(float v) { return fmaxf(v, 0.0f); }

// LDS weight layout (176 floats; every f32x4 row 16B-aligned):
// [0..7] w0x[o]  [8..15] w0y[o]  [16..23] b0[o]
// [24..87] w0t[ch][o] (8 rows of 8)  [88..151] w1t[i][o] (8 rows of 8)
// [152..159] w2[o]  [160..167] b1[o]  [168] b2

__global__ __launch_bounds__(256) void dmh_kernel(
    const float* __restrict__ mask_feats,   // (4,8,128,192)
    const float* __restrict__ params,       // (128,169)
    const float* __restrict__ locs,         // (128,2)
    const float* __restrict__ soi,          // (5,)
    const int*   __restrict__ im_inds,      // (128,)
    const int*   __restrict__ fpn_levels,   // (128,)
    const int*   __restrict__ stride_p,     // scalar (=8)
    float*       __restrict__ out)          // (128,1,256,384)
{
    const int tid = threadIdx.x;
    const int c0 = blockIdx.x * 64;   // source col tile origin
    const int r0 = blockIdx.y * 32;   // source row tile origin
    const int n  = blockIdx.z;        // instance

    __shared__ float sW[176];
    __shared__ float tile[33 * 66];   // rows -1..31 -> 0..32, cols -1..63 -> 0..64

    // ---- stage + transpose weights into LDS ----
    if (tid < 169) {
        float v = params[(size_t)n * 169 + tid];
        int d;
        if (tid < 80)       { int o = tid / 10, r = tid - o * 10;
                              d = (r == 0) ? o : (r == 1) ? (8 + o) : (24 + (r - 2) * 8 + o); }
        else if (tid < 144) { int t = tid - 80, o = t >> 3, i = t & 7; d = 88 + i * 8 + o; }
        else if (tid < 152) d = 152 + (tid - 144);
        else if (tid < 160) d = 16 + (tid - 152);
        else if (tid < 168) d = 160 + (tid - 160);
        else                d = 168;
        sW[d] = v;
    }

    const int   stride = *stride_p;                 // 8
    const float half   = 0.5f * (float)stride;      // 4.0
    const float locx = locs[2 * n + 0];
    const float locy = locs[2 * n + 1];
    const float inv  = 1.0f / soi[fpn_levels[n]];
    const float* fb  = mask_feats + (size_t)im_inds[n] * 8 * HW;

    // ---- interior geometry: 2 rows x 4 cols per thread; issue all 16 loads
    //      BEFORE the staging barrier (latency hides under barrier wait) ----
    const int ir  = (tid >> 4) * 2;     // 0,2,...,30
    const int ic  = (tid & 15) * 4;     // 0,4,...,60
    const int rA  = r0 + ir;            // always in-bounds
    const int cc0 = c0 + ic;
    const float* fpA = fb + rA * WW + cc0;

    f32x4 xA[8], xB[8];
    #pragma unroll
    for (int ch = 0; ch < 8; ++ch) {
        xA[ch] = *reinterpret_cast<const f32x4*>(fpA + ch * HW);
        xB[ch] = *reinterpret_cast<const f32x4*>(fpA + ch * HW + WW);
    }

    __syncthreads();

    const f32x4* __restrict__ sW4 = reinterpret_cast<const f32x4*>(sW);

    // ---------- phase 1a: interior MLP, 8 px per thread, A/B interleaved ----------
    {
        const float rxd = -(float)stride * inv;
        float rx[4];
        rx[0] = (locx - (float)(cc0 * stride) - half) * inv;
        rx[1] = rx[0] + rxd; rx[2] = rx[1] + rxd; rx[3] = rx[2] + rxd;
        const float ryA = (locy - (float)(rA * stride) - half) * inv;
        const float ryB = ryA - (float)stride * inv;

        f32x4 w0xL = sW4[0], w0xH = sW4[1];
        f32x4 w0yL = sW4[2], w0yH = sW4[3];
        f32x4 b0L  = sW4[4], b0H  = sW4[5];

        float hA[8][4], hB[8][4];
        #pragma unroll
        for (int o = 0; o < 8; ++o) {
            float wx = (o < 4) ? w0xL[o] : w0xH[o - 4];
            float wy = (o < 4) ? w0yL[o] : w0yH[o - 4];
            float b  = (o < 4) ? b0L[o]  : b0H[o - 4];
            float tA = fmaf(wy, ryA, b);
            float tB = fmaf(wy, ryB, b);
            #pragma unroll
            for (int j = 0; j < 4; ++j) {
                hA[o][j] = fmaf(wx, rx[j], tA);
                hB[o][j] = fmaf(wx, rx[j], tB);
            }
        }
        #pragma unroll
        for (int ch = 0; ch < 8; ++ch) {
            f32x4 wL = sW4[6 + 2 * ch];
            f32x4 wH = sW4[7 + 2 * ch];
            #pragma unroll
            for (int o = 0; o < 8; ++o) {
                float w = (o < 4) ? wL[o] : wH[o - 4];
                #pragma unroll
                for (int j = 0; j < 4; ++j) {
                    hA[o][j] = fmaf(w, xA[ch][j], hA[o][j]);
                    hB[o][j] = fmaf(w, xB[ch][j], hB[o][j]);
                }
            }
        }

        float aA[8][4], aB[8][4];
        {
            f32x4 b1L = sW4[40], b1H = sW4[41];
            #pragma unroll
            for (int o = 0; o < 8; ++o) {
                float b = (o < 4) ? b1L[o] : b1H[o - 4];
                #pragma unroll
                for (int j = 0; j < 4; ++j) { aA[o][j] = b; aB[o][j] = b; }
            }
        }
        #pragma unroll
        for (int i = 0; i < 8; ++i) {
            f32x4 wL = sW4[22 + 2 * i];
            f32x4 wH = sW4[23 + 2 * i];
            float vA[4], vB[4];
            #pragma unroll
            for (int j = 0; j < 4; ++j) { vA[j] = relu(hA[i][j]); vB[j] = relu(hB[i][j]); }
            #pragma unroll
            for (int o = 0; o < 8; ++o) {
                float w = (o < 4) ? wL[o] : wH[o - 4];
                #pragma unroll
                for (int j = 0; j < 4; ++j) {
                    aA[o][j] = fmaf(w, vA[j], aA[o][j]);
                    aB[o][j] = fmaf(w, vB[j], aB[o][j]);
                }
            }
        }

        f32x4 w2L = sW4[38], w2H = sW4[39];
        const float b2v = sW[168];
        float lgA[4] = {b2v, b2v, b2v, b2v};
        float lgB[4] = {b2v, b2v, b2v, b2v};
        #pragma unroll
        for (int o = 0; o < 8; ++o) {
            float w2 = (o < 4) ? w2L[o] : w2H[o - 4];
            #pragma unroll
            for (int j = 0; j < 4; ++j) {
                lgA[j] = fmaf(w2, relu(aA[o][j]), lgA[j]);
                lgB[j] = fmaf(w2, relu(aB[o][j]), lgB[j]);
            }
        }
        #pragma unroll
        for (int j = 0; j < 4; ++j) {
            tile[(ir + 1) * 66 + ic + 1 + j] = lgA[j];
            tile[(ir + 2) * 66 + ic + 1 + j] = lgB[j];
        }
    }

    // ---------- phase 1b: 97 halo px (row -1, col -1), scalar ----------
    if (tid < 97) {
        int r, c;
        if (tid < 65) { r = -1; c = tid - 1; }      // row -1, cols -1..63
        else          { r = tid - 65; c = -1; }     // rows 0..31, col -1
        int hr = min(max(r0 + r, 0), HH - 1);
        int hc = min(max(c0 + c, 0), WW - 1);
        const float* hfp = fb + hr * WW + hc;
        float rx  = (locx - (float)(hc * stride) - half) * inv;
        float ry2 = (locy - (float)(hr * stride) - half) * inv;
        float hh[8];
        #pragma unroll
        for (int o = 0; o < 8; ++o)
            hh[o] = fmaf(sW[o], rx, fmaf(sW[8 + o], ry2, sW[16 + o]));
        #pragma unroll
        for (int ch = 0; ch < 8; ++ch) {
            float x = hfp[ch * HW];
            #pragma unroll
            for (int o = 0; o < 8; ++o) hh[o] = fmaf(sW[24 + ch * 8 + o], x, hh[o]);
        }
        float aa[8];
        #pragma unroll
        for (int o = 0; o < 8; ++o) aa[o] = sW[160 + o];
        #pragma unroll
        for (int i = 0; i < 8; ++i) {
            float v = relu(hh[i]);
            #pragma unroll
            for (int o = 0; o < 8; ++o) aa[o] = fmaf(sW[88 + i * 8 + o], v, aa[o]);
        }
        float lg = sW[168];
        #pragma unroll
        for (int o = 0; o < 8; ++o) lg = fmaf(sW[152 + o], relu(aa[o]), lg);
        tile[(r + 1) * 66 + (c + 1)] = lg;
    }
    __syncthreads();

    // ---------- phase 2: x2 aligned upsample -> 64x128 output tile ----------
    const int kx = tid & 31;          // 32 groups of 4 output cols
    const int ky = tid >> 5;          // 8 row groups of 8 rows
    float* ob = out + ((size_t)n * 256 + 2 * r0) * 384 + 2 * c0 + 4 * kx;
    #pragma unroll
    for (int yy = 0; yy < 8; ++yy) {
        int yt = ky * 8 + yy;         // 0..63
        int iy = yt - 1;
        int rbl = iy >> 1;            // arithmetic shift handles iy=-1
        int fy = iy & 1;
        float wy0 = fy ? 0.5f : 1.0f;
        float wy1 = fy ? 0.5f : 0.0f;
        int sr  = rbl + 1;            // in [0,32]
        int sr2 = sr + fy;            // in [0,32]
        const float* ra = &tile[sr  * 66 + 2 * kx];
        const float* rc = &tile[sr2 * 66 + 2 * kx];
        float t0 = fmaf(wy1, rc[0], wy0 * ra[0]);
        float t1 = fmaf(wy1, rc[1], wy0 * ra[1]);
        float t2 = fmaf(wy1, rc[2], wy0 * ra[2]);
        f32x4 o4;
        o4.x = 0.5f * (t0 + t1);
        o4.y = t1;
        o4.z = 0.5f * (t1 + t2);
        o4.w = t2;
        __builtin_nontemporal_store(o4, reinterpret_cast<f32x4*>(ob + (size_t)yt * 384));
    }
}

extern "C" void kernel_launch(void* const* d_in, const int* in_sizes, int n_in,
                              void* d_out, int out_size, void* d_ws, size_t ws_size,
                              hipStream_t stream) {
    const float* mask_feats = (const float*)d_in[0];
    const float* params     = (const float*)d_in[1];
    const float* locs       = (const float*)d_in[2];
    const float* soi        = (const float*)d_in[3];
    const int*   im_inds    = (const int*)d_in[4];
    const int*   fpn_levels = (const int*)d_in[5];
    const int*   stride_p   = (const int*)d_in[6];
    float* out = (float*)d_out;

    dim3 grid(WW / 64, HH / 32, 128);   // (3, 4, 128)
    dim3 block(256);
    dmh_kernel<<<grid, block, 0, stream>>>(
        mask_feats, params, locs, soi, im_inds, fpn_levels, stride_p, out);
}

// Round 11
// 20.438 us; speedup vs baseline: 1.2191x; 1.0414x over previous
//
#include <hip/hip_runtime.h>

#define HH 128
#define WW 192
#define HW (HH * WW)

typedef float f32x4 __attribute__((ext_vector_type(4)));
typedef __fp16 h2 __attribute__((ext_vector_type(2)));

__device__ __forceinline__ float relu(float v) { return fmaxf(v, 0.0f); }

__device__ __forceinline__ float fdot2(h2 a, h2 b, float c) {
#if __has_builtin(__builtin_amdgcn_fdot2)
    return __builtin_amdgcn_fdot2(a, b, c, false);
#else
    return fmaf((float)a.x, (float)b.x, fmaf((float)a.y, (float)b.y, c));
#endif
}
__device__ __forceinline__ h2 pkrtz(float a, float b) {
    return __builtin_amdgcn_cvt_pkrtz(a, b);
}

// LDS packed-weight layout:
//   sWp (h2 units): [0..31]  w0feat: slot o*4+p = (w0[o][2+2p], w0[o][3+2p])
//                   [32..63] w1:     slot 32+o*4+p = (w1[o][2p], w1[o][2p+1])
//                   [64..67] w2:     slot 64+p = (w2[2p], w2[2p+1])
//   sF (floats):    [0..7] w0x  [8..15] w0y  [16..23] b0  [24..31] b1  [32] b2

__global__ __launch_bounds__(512) void dmh_kernel(
    const float* __restrict__ mask_feats,   // (4,8,128,192)
    const float* __restrict__ params,       // (128,169)
    const float* __restrict__ locs,         // (128,2)
    const float* __restrict__ soi,          // (5,)
    const int*   __restrict__ im_inds,      // (128,)
    const int*   __restrict__ fpn_levels,   // (128,)
    const int*   __restrict__ stride_p,     // scalar (=8)
    float*       __restrict__ out)          // (128,1,256,384)
{
    const int tid = threadIdx.x;
    const int c0 = blockIdx.x * 64;   // source col tile origin
    const int r0 = blockIdx.y * 32;   // source row tile origin
    const int n  = blockIdx.z;        // instance

    __shared__ h2    sWp[68];
    __shared__ float sF[33];
    __shared__ float tile[33 * 66];   // rows -1..31 -> 0..32, cols -1..63 -> 0..64

    // ---- stage weights: fp16-pack matmul weights, fp32 for coords/biases ----
    if (tid < 169) {
        float v = params[(size_t)n * 169 + tid];
        __fp16* sWh = reinterpret_cast<__fp16*>(sWp);
        if (tid < 80) {
            int o = tid / 10, k = tid - o * 10;
            if (k == 0)      sF[o] = v;
            else if (k == 1) sF[8 + o] = v;
            else { int f = k - 2; sWh[(o * 4 + (f >> 1)) * 2 + (f & 1)] = (__fp16)v; }
        } else if (tid < 144) {
            int t = tid - 80, o = t >> 3, i = t & 7;
            sWh[(32 + o * 4 + (i >> 1)) * 2 + (i & 1)] = (__fp16)v;
        } else if (tid < 152) {
            int o = tid - 144;
            sWh[(64 + (o >> 1)) * 2 + (o & 1)] = (__fp16)v;
        } else if (tid < 160) sF[16 + (tid - 152)] = v;   // b0
        else if (tid < 168)   sF[24 + (tid - 160)] = v;   // b1
        else                  sF[32] = v;                  // b2
    }

    const int   stride = *stride_p;                 // 8
    const float half_s = 0.5f * (float)stride;      // 4.0
    const float locx = locs[2 * n + 0];
    const float locy = locs[2 * n + 1];
    const float inv  = 1.0f / soi[fpn_levels[n]];
    const float* fb  = mask_feats + (size_t)im_inds[n] * 8 * HW;

    // ---- interior geometry: 1 row x 4 cols per thread; loads pre-barrier ----
    const int ir = tid >> 4;          // 0..31
    const int ic = (tid & 15) << 2;   // 0,4,...,60
    const int rr = r0 + ir, cc = c0 + ic;
    const float* fp = fb + rr * WW + cc;

    f32x4 xv[8];
    #pragma unroll
    for (int ch = 0; ch < 8; ++ch)
        xv[ch] = *reinterpret_cast<const f32x4*>(fp + ch * HW);

    __syncthreads();

    // ---------- phase 1a: interior MLP via v_dot2_f32_f16 ----------
    {
        const float rxd = -(float)stride * inv;
        float rx[4];
        rx[0] = (locx - (float)(cc * stride) - half_s) * inv;
        rx[1] = rx[0] + rxd; rx[2] = rx[1] + rxd; rx[3] = rx[2] + rxd;
        const float ry = (locy - (float)(rr * stride) - half_s) * inv;

        // pack feats to half2 channel-pairs
        h2 xp[4][4];
        #pragma unroll
        for (int p = 0; p < 4; ++p)
            #pragma unroll
            for (int j = 0; j < 4; ++j)
                xp[p][j] = pkrtz(xv[2 * p][j], xv[2 * p + 1][j]);

        float h[8][4];
        #pragma unroll
        for (int o = 0; o < 8; ++o) {
            const h2 w0 = sWp[o * 4 + 0], w1 = sWp[o * 4 + 1],
                     w2 = sWp[o * 4 + 2], w3 = sWp[o * 4 + 3];
            float tO = fmaf(sF[8 + o], ry, sF[16 + o]);
            float wx = sF[o];
            #pragma unroll
            for (int j = 0; j < 4; ++j) {
                float acc = fmaf(wx, rx[j], tO);
                acc = fdot2(w0, xp[0][j], acc);
                acc = fdot2(w1, xp[1][j], acc);
                acc = fdot2(w2, xp[2][j], acc);
                acc = fdot2(w3, xp[3][j], acc);
                h[o][j] = acc;
            }
        }

        h2 hp[4][4];
        #pragma unroll
        for (int p = 0; p < 4; ++p)
            #pragma unroll
            for (int j = 0; j < 4; ++j)
                hp[p][j] = pkrtz(relu(h[2 * p][j]), relu(h[2 * p + 1][j]));

        float a[8][4];
        #pragma unroll
        for (int o = 0; o < 8; ++o) {
            const h2 w0 = sWp[32 + o * 4 + 0], w1 = sWp[32 + o * 4 + 1],
                     w2 = sWp[32 + o * 4 + 2], w3 = sWp[32 + o * 4 + 3];
            float b1 = sF[24 + o];
            #pragma unroll
            for (int j = 0; j < 4; ++j) {
                float acc = b1;
                acc = fdot2(w0, hp[0][j], acc);
                acc = fdot2(w1, hp[1][j], acc);
                acc = fdot2(w2, hp[2][j], acc);
                acc = fdot2(w3, hp[3][j], acc);
                a[o][j] = acc;
            }
        }

        const h2 v0 = sWp[64], v1 = sWp[65], v2 = sWp[66], v3 = sWp[67];
        const float b2v = sF[32];
        #pragma unroll
        for (int j = 0; j < 4; ++j) {
            h2 a0 = pkrtz(relu(a[0][j]), relu(a[1][j]));
            h2 a1 = pkrtz(relu(a[2][j]), relu(a[3][j]));
            h2 a2 = pkrtz(relu(a[4][j]), relu(a[5][j]));
            h2 a3 = pkrtz(relu(a[6][j]), relu(a[7][j]));
            float lg = b2v;
            lg = fdot2(v0, a0, lg);
            lg = fdot2(v1, a1, lg);
            lg = fdot2(v2, a2, lg);
            lg = fdot2(v3, a3, lg);
            tile[(ir + 1) * 66 + ic + 1 + j] = lg;
        }
    }

    // ---------- phase 1b: 97 halo px, same fp16-dot2 math, 1 px ----------
    if (tid < 97) {
        int r, c;
        if (tid < 65) { r = -1; c = tid - 1; }      // row -1, cols -1..63
        else          { r = tid - 65; c = -1; }     // rows 0..31, col -1
        int hr = min(max(r0 + r, 0), HH - 1);
        int hc = min(max(c0 + c, 0), WW - 1);
        const float* hfp = fb + hr * WW + hc;
        float rx  = (locx - (float)(hc * stride) - half_s) * inv;
        float ry2 = (locy - (float)(hr * stride) - half_s) * inv;
        h2 xp[4];
        #pragma unroll
        for (int p = 0; p < 4; ++p)
            xp[p] = pkrtz(hfp[(2 * p) * HW], hfp[(2 * p + 1) * HW]);
        float hh[8];
        #pragma unroll
        for (int o = 0; o < 8; ++o) {
            float acc = fmaf(sF[o], rx, fmaf(sF[8 + o], ry2, sF[16 + o]));
            #pragma unroll
            for (int p = 0; p < 4; ++p) acc = fdot2(sWp[o * 4 + p], xp[p], acc);
            hh[o] = acc;
        }
        h2 hp[4];
        #pragma unroll
        for (int p = 0; p < 4; ++p)
            hp[p] = pkrtz(relu(hh[2 * p]), relu(hh[2 * p + 1]));
        float aa[8];
        #pragma unroll
        for (int o = 0; o < 8; ++o) {
            float acc = sF[24 + o];
            #pragma unroll
            for (int p = 0; p < 4; ++p) acc = fdot2(sWp[32 + o * 4 + p], hp[p], acc);
            aa[o] = acc;
        }
        float lg = sF[32];
        #pragma unroll
        for (int p = 0; p < 4; ++p) {
            h2 ap = pkrtz(relu(aa[2 * p]), relu(aa[2 * p + 1]));
            lg = fdot2(sWp[64 + p], ap, lg);
        }
        tile[(r + 1) * 66 + (c + 1)] = lg;
    }
    __syncthreads();

    // ---------- phase 2: x2 aligned upsample -> 64x128 output tile ----------
    const int kx = tid & 31;          // 32 groups of 4 output cols
    const int ky = tid >> 5;          // 16 row groups of 4 rows
    float* ob = out + ((size_t)n * 256 + 2 * r0) * 384 + 2 * c0 + 4 * kx;
    #pragma unroll
    for (int yy = 0; yy < 4; ++yy) {
        int yt = ky * 4 + yy;         // 0..63
        int iy = yt - 1;
        int rbl = iy >> 1;            // arithmetic shift handles iy=-1
        int fy = iy & 1;
        float wy0 = fy ? 0.5f : 1.0f;
        float wy1 = fy ? 0.5f : 0.0f;
        int sr  = rbl + 1;            // in [0,32]
        int sr2 = sr + fy;            // in [0,32]
        const float* ra = &tile[sr  * 66 + 2 * kx];
        const float* rc = &tile[sr2 * 66 + 2 * kx];
        float t0 = fmaf(wy1, rc[0], wy0 * ra[0]);
        float t1 = fmaf(wy1, rc[1], wy0 * ra[1]);
        float t2 = fmaf(wy1, rc[2], wy0 * ra[2]);
        f32x4 o4;
        o4.x = 0.5f * (t0 + t1);
        o4.y = t1;
        o4.z = 0.5f * (t1 + t2);
        o4.w = t2;
        __builtin_nontemporal_store(o4, reinterpret_cast<f32x4*>(ob + (size_t)yt * 384));
    }
}

extern "C" void kernel_launch(void* const* d_in, const int* in_sizes, int n_in,
                              void* d_out, int out_size, void* d_ws, size_t ws_size,
                              hipStream_t stream) {
    const float* mask_feats = (const float*)d_in[0];
    const float* params     = (const float*)d_in[1];
    const float* locs       = (const float*)d_in[2];
    const float* soi        = (const float*)d_in[3];
    const int*   im_inds    = (const int*)d_in[4];
    const int*   fpn_levels = (const int*)d_in[5];
    const int*   stride_p   = (const int*)d_in[6];
    float* out = (float*)d_out;

    dim3 grid(WW / 64, HH / 32, 128);   // (3, 4, 128)
    dim3 block(512);
    dmh_kernel<<<grid, block, 0, stream>>>(
        mask_feats, params, locs, soi, im_inds, fpn_levels, stride_p, out);
}